// Round 4
// baseline (85.140 us; speedup 1.0000x reference)
//
#include <hip/hip_runtime.h>
#include <hip/hip_bf16.h>
#include <math.h>

// EquivEncoder: B=16, N_CTX=1024, 64x64 grid, fp32.
// out[b,c,iy,ix]: c0 = dens = sum_n w, c1 = (sum_n w*y0)/dens, c2 = (sum_n w*y1)/dens
// w = exp2(s*dx^2)*exp2(s*dy^2), s = -0.5*log2(e)*exp(-2*logl)
//
// R4 design (R2==R3 showed the limiter is dispatch count, not any pipe):
//  - SINGLE kernel, no workspace: 256 blocks = 16 b x 16 iy-tiles (4 iy x 64 ix),
//    1 cell/thread. Each block scans all 1024 n in 16 chunks of 64.
//  - double-buffered LDS tables per chunk: wx[64][64], wyt[64][4] premultiplied
//    {wy, wy*y0, wy*y1} -> inner loop = 1 b32 read + 1 broadcast b128 + 3 FMA per n.
//  - software pipeline: global loads for chunk c+1 issued BEFORE inner(c),
//    exp2+LDS writes after; one barrier per chunk.

#define NCTX  1024
#define NG    4096
#define NCH   64      // chunk size
#define NCHUNK 16

__global__ __launch_bounds__(256)
void ee_fused(const float* __restrict__ X,
              const float* __restrict__ Y,
              const float* __restrict__ log_l_scale,
              float* __restrict__ out) {
    const int b   = blockIdx.x >> 4;
    const int t   = blockIdx.x & 15;
    const int iy0 = t * 4;
    const int tid = threadIdx.x;
    const int ix  = tid & 63;     // lane = ix
    const int iyl = tid >> 6;     // wave id = iy row within tile

    const float step  = 20.0f / 63.0f;
    const float scale = -0.72134752044448170f * expf(-2.0f * log_l_scale[0]);
    const float gx    = -10.0f + step * (float)ix;

    __shared__ float  wx [2][NCH][64];   // 32 KB
    __shared__ float4 wyt[2][NCH][4];    // 8 KB  {wy, wy*y0, wy*y1, -}

    const float2* Xb = (const float2*)(X + (size_t)b * NCTX * 2);
    const float2* Yb = (const float2*)(Y + (size_t)b * NCTX * 2);

    // pipeline registers for next chunk's staging inputs
    float  xr[16];      // X[n].x for the 16 n this thread tables (wx)
    float2 xw, yw;      // X[n], Y[n] for the 1 n this thread tables (wyt)
    const int jw = tid >> 2;        // wyt: n index
    const int qw = tid & 3;         // wyt: iy-local
    const float gyq = 10.0f - step * (float)(iy0 + qw);

    auto load_chunk = [&](int c) {
        const int n0 = c * NCH;
#pragma unroll
        for (int k = 0; k < 16; ++k)
            xr[k] = Xb[n0 + (tid >> 6) + k * 4].x;   // wave-uniform -> s_load
        xw = Xb[n0 + jw];
        yw = Yb[n0 + jw];
    };
    auto store_tables = [&](int p) {
        const float dy = gyq - xw.y;
        const float wy = exp2f(dy * dy * scale);
        wyt[p][jw][qw] = make_float4(wy, wy * yw.x, wy * yw.y, 0.0f);
#pragma unroll
        for (int k = 0; k < 16; ++k) {
            const float dx = gx - xr[k];
            wx[p][(tid >> 6) + k * 4][ix] = exp2f(dx * dx * scale);  // row write: free
        }
    };

    load_chunk(0);
    store_tables(0);
    __syncthreads();

    float d = 0.0f, a1 = 0.0f, a2 = 0.0f;
    for (int c = 0; c < NCHUNK; ++c) {
        const int p = c & 1;
        if (c + 1 < NCHUNK) load_chunk(c + 1);   // loads in flight during inner
#pragma unroll 8
        for (int n = 0; n < NCH; ++n) {
            const float  wxv = wx[p][n][ix];     // 64 consecutive b32: 2-way, free
            const float4 wv  = wyt[p][n][iyl];   // wave-uniform broadcast b128
            d  = fmaf(wxv, wv.x, d);
            a1 = fmaf(wxv, wv.y, a1);
            a2 = fmaf(wxv, wv.z, a2);
        }
        if (c + 1 < NCHUNK) store_tables(p ^ 1); // exps after inner hid load latency
        __syncthreads();                          // one barrier per chunk
    }

    const int g = (iy0 + iyl) * 64 + ix;
    const float inv = 1.0f / d;                   // d > 0 (sum of exps)
    float* ob = out + (size_t)b * 3 * NG;
    ob[g]          = d;
    ob[NG + g]     = a1 * inv;
    ob[2 * NG + g] = a2 * inv;
}

extern "C" void kernel_launch(void* const* d_in, const int* in_sizes, int n_in,
                              void* d_out, int out_size, void* d_ws, size_t ws_size,
                              hipStream_t stream) {
    const float* X    = (const float*)d_in[0];   // (16,1024,2) fp32
    const float* Y    = (const float*)d_in[1];   // (16,1024,2) fp32
    const float* logl = (const float*)d_in[2];   // scalar fp32
    float* out = (float*)d_out;                  // (16,3,64,64) fp32

    ee_fused<<<dim3(256), dim3(256), 0, stream>>>(X, Y, logl, out);
}